// Round 10
// baseline (145.884 us; speedup 1.0000x reference)
//
#include <hip/hip_runtime.h>
#include <stdint.h>

#define B_   256
#define O_   128
#define D_   128
#define IN_  16384
#define NEGF (-9.0e15f)
#define TINYF 1.1754943508222875e-38f

// ---------------- threefry2x32 (JAX partitionable, 20 rounds) ----------------
__device__ __forceinline__ void tf2x32(uint32_t k0, uint32_t k1,
                                       uint32_t x0, uint32_t x1,
                                       uint32_t* o0, uint32_t* o1) {
  uint32_t k2 = k0 ^ k1 ^ 0x1BD11BDAu;
#define TFR(r) { x0 += x1; x1 = (x1 << (r)) | (x1 >> (32 - (r))); x1 ^= x0; }
  x0 += k0; x1 += k1;
  TFR(13) TFR(15) TFR(26) TFR(6)
  x0 += k1; x1 += k2 + 1u;
  TFR(17) TFR(29) TFR(16) TFR(24)
  x0 += k2; x1 += k0 + 2u;
  TFR(13) TFR(15) TFR(26) TFR(6)
  x0 += k0; x1 += k1 + 3u;
  TFR(17) TFR(29) TFR(16) TFR(24)
  x0 += k1; x1 += k2 + 4u;
  TFR(13) TFR(15) TFR(26) TFR(6)
  x0 += k2; x1 += k0 + 5u;
#undef TFR
  *o0 = x0; *o1 = x1;
}

__device__ __forceinline__ float gumbel_bits(uint32_t bits) {
  float f = __uint_as_float((bits >> 9) | 0x3f800000u) - 1.0f;  // [0,1)
  float u = fmaxf(TINYF, f + TINYF);
  return -logf(-logf(u));
}

__device__ __forceinline__ uint32_t mono32(float x) {
  int b = __float_as_int(x);
  return (uint32_t)b ^ ((uint32_t)(b >> 31) | 0x80000000u);
}

__device__ __forceinline__ float rl_f(float v, int l) {
  return __int_as_float(__builtin_amdgcn_readlane(__float_as_int(v), l));
}

// DPP helpers (identical trees to the rounds 5-10 passing trajectory)
#define DPPF(x, ctrl) __int_as_float(__builtin_amdgcn_mov_dpp( \
    __float_as_int(x), (ctrl), 0xf, 0xf, true))
#define DPPU(x, ctrl) ((uint32_t)__builtin_amdgcn_mov_dpp( \
    (int)(x), (ctrl), 0xf, 0xf, true))

__device__ __forceinline__ float wredmaxf(float x) {
  x = fmaxf(x, DPPF(x, 0xB1));
  x = fmaxf(x, DPPF(x, 0x4E));
  x = fmaxf(x, DPPF(x, 0x141));
  x = fmaxf(x, DPPF(x, 0x140));
  x = fmaxf(x, DPPF(x, 0x142));   // row_bcast15
  x = fmaxf(x, DPPF(x, 0x143));   // row_bcast31
  return rl_f(x, 63);
}
__device__ __forceinline__ float wredsumf(float x) {
  x = x + DPPF(x, 0xB1);
  x = x + DPPF(x, 0x4E);
  x = x + DPPF(x, 0x141);
  x = x + DPPF(x, 0x140);
  x = x + DPPF(x, 0x142);
  x = x + DPPF(x, 0x143);
  return rl_f(x, 63);
}
// u32 max over 64 lanes, same lane-movement tree (validated geometry)
__device__ __forceinline__ uint32_t wredmaxu_to63(uint32_t x) {
  uint32_t t;
  t = DPPU(x, 0xB1);  x = x > t ? x : t;
  t = DPPU(x, 0x4E);  x = x > t ? x : t;
  t = DPPU(x, 0x141); x = x > t ? x : t;
  t = DPPU(x, 0x140); x = x > t ? x : t;
  t = DPPU(x, 0x142); x = x > t ? x : t;
  t = DPPU(x, 0x143); x = x > t ? x : t;
  return x;
}

// ---------------- Kernel A: M[b][p][o] = <enc[b,p,:], W[o, p*D:(p+1)*D]> ----
// (validated: 64o x 128b tiles, W half-tile in LDS, enc streamed+prefetch)
__global__ __launch_bounds__(256, 2) void build_M(
    const float* __restrict__ enc, const float* __restrict__ W,
    float* __restrict__ M) {
  const int p   = blockIdx.x;
  const int og0 = (blockIdx.y & 1) * 64;    // o-half base
  const int b0  = (blockIdx.y >> 1) * 128;  // b-half base
  const int t   = threadIdx.x;

  __shared__ float Ws[64 * 132];            // 33.8 KB

  {
    const int rgrp = t >> 5;
    const int c16  = t & 31;
#pragma unroll
    for (int k = 0; k < 8; k++) {
      int row = k * 8 + rgrp;
      *(float4*)(Ws + row * 132 + c16 * 4) =
          *(const float4*)(W + (size_t)(og0 + row) * IN_ + p * D_ + c16 * 4);
    }
  }

  const int og = t & 15;
  const int bg = t >> 4;

  const float* eb = enc + ((size_t)(b0 + bg) * O_ + p) * D_;
  const size_t bstride = (size_t)16 * O_ * D_;

  float4 ev[8], evn[8];
#pragma unroll
  for (int bi = 0; bi < 8; bi++)
    ev[bi] = *(const float4*)(eb + bi * bstride);

  __syncthreads();

  float acc0[8][4] = {}, acc1[8][4] = {};

  for (int dc = 0; dc < 128; dc += 4) {
    if (dc < 124) {
#pragma unroll
      for (int bi = 0; bi < 8; bi++)
        evn[bi] = *(const float4*)(eb + bi * bstride + dc + 4);
    }
    float4 wv[4];
#pragma unroll
    for (int oi = 0; oi < 4; oi++)
      wv[oi] = *(const float4*)(Ws + (og + 16 * oi) * 132 + dc);
#pragma unroll
    for (int bi = 0; bi < 8; bi++)
#pragma unroll
      for (int oi = 0; oi < 4; oi++) {
        acc0[bi][oi] += ev[bi].x * wv[oi].x;
        acc1[bi][oi] += ev[bi].y * wv[oi].y;
        acc0[bi][oi] += ev[bi].z * wv[oi].z;
        acc1[bi][oi] += ev[bi].w * wv[oi].w;
      }
#pragma unroll
    for (int bi = 0; bi < 8; bi++) ev[bi] = evn[bi];
  }

#pragma unroll
  for (int bi = 0; bi < 8; bi++) {
    int b = b0 + bg + 16 * bi;
#pragma unroll
    for (int oi = 0; oi < 4; oi++) {
      int o = og0 + og + 16 * oi;
      M[((size_t)b * O_ + p) * O_ + o] = acc0[bi][oi] + acc1[bi][oi];
    }
  }
}

// ---------------- Kernel S: pipelined sampler v7 ----------------------------
// v6 + SIMD-0 evacuation:
//   - wave 4 (shares SIMD 0 with chain wave 0) does ONLY the two cooperative
//     early-gumbel chunks (~2 us), then parks at the final barrier (a
//     barrier-parked wave issues nothing -> wave 0 owns SIMD 0's issue slots
//     for the whole chain).
//   - solo gumbel chunks 2..15 -> waves 5-7 (w5: 2,5,8,11,14; w6: 3,6,9,12,15;
//     w7: 4,7,10,13); each produced >=3x earlier than the chain consumes it.
//   - phase-3 remapped to 6 waves {1,2,3,5,6,7}: chunk = wi + 6k,
//     wi = (w<4) ? w-1 : w-2 -> exact 1:1 cover of chunks 0..19.
// All selection/ls/err numerics bit-identical to v6 (validated).
__global__ __launch_bounds__(512, 1) void sampler(
    const float* __restrict__ M, const float* __restrict__ bias,
    const float* __restrict__ enc, const float* __restrict__ W, int use_M,
    float* __restrict__ out_pos, float* __restrict__ out_ls,
    float* __restrict__ out_err) {
  const int b = blockIdx.x;
  const int t = threadIdx.x;
  const int lane = t & 63;
  const int w = t >> 6;

  // interleaved: Mlds[p*128 + 2*k + h] = M[b][p][h*64+k]
  __shared__ float  Mlds[O_ * O_];          // 64 KB
  __shared__ float  Glds[O_ * O_];          // 64 KB, Glds[j*128+2*lane+h]
  __shared__ double snapPd[20 * 64 * 2];    // 20 KB
  __shared__ unsigned long long snapMk[20 * 2];
  __shared__ unsigned long long posPk[20];  // packed positions per chunk
  __shared__ double lsSlot[20];
  __shared__ int    errSlot[20];
  __shared__ int    flagG[16];              // gumbel chunk ready
  __shared__ int    chainRel[20];           // chain chunk released
  __shared__ int    stageDone;              // staging waves 1-3 done count
  __shared__ int    g0cnt, g1cnt;           // coop chunk-0/1 counters
  __shared__ double partPd[3][64][2];       // quarters 1-3 f64 column sums
  __shared__ uint32_t Klds[O_ * 2];         // step keys

  volatile int* vFlagG = flagG;
  volatile int* vRel   = chainRel;
  volatile int* vSD    = &stageDone;

  const float b1f = bias[lane], b2f = bias[lane + 64];

  // ---------- init: flags + step-key table, then start barrier -------------
  if (t < O_) {
    uint32_t a, bb;
    tf2x32(0u, 42u, 0u, (uint32_t)t, &a, &bb);
    Klds[2 * t] = a; Klds[2 * t + 1] = bb;
  }
  if (t < 16) flagG[t] = 0;
  if (t >= 32 && t < 52) chainRel[t - 32] = 0;
  if (t == 64) stageDone = 0;
  if (t == 65) g0cnt = 0;
  if (t == 66) g1cnt = 0;
  __syncthreads();

  // ---------- staging (+ f64 partial column sums), waves 0-3 ----------
  double pq1 = 0.0, pq2 = 0.0;   // wave-0 in-register quarter partial
  if (!use_M) {
    for (int idx = t; idx < O_ * O_; idx += 512) {
      int p = idx >> 7, o = idx & 127;
      const float* er = enc + ((size_t)b * O_ + p) * D_;
      const float* wr = W + (size_t)o * IN_ + p * D_;
      float s = 0.f;
      for (int d = 0; d < D_; d += 4) {
        float4 e4 = *(const float4*)(er + d);
        float4 w4 = *(const float4*)(wr + d);
        s += e4.x * w4.x + e4.y * w4.y + e4.z * w4.z + e4.w * w4.w;
      }
      Mlds[p * O_ + ((o & 63) << 1) + (o >> 6)] = s;
    }
    __syncthreads();
    if (w < 4) {
      double P1 = 0.0, P2 = 0.0;
      for (int p = 32 * w; p < 32 * w + 32; p++) {
        float2 mv = *(float2*)&Mlds[p * O_ + 2 * lane];
        P1 += (double)mv.x;
        P2 += (double)mv.y;
      }
      if (w == 0) { pq1 = P1; pq2 = P2; }
      else {
        partPd[w - 1][lane][0] = P1; partPd[w - 1][lane][1] = P2;
        __threadfence_block();
        if (lane == 0) atomicAdd(&stageDone, 1);
      }
    }
  } else if (w < 4) {
    const float* Mb = M + (size_t)b * O_ * O_;
    double P1 = 0.0, P2 = 0.0;
    for (int p = 32 * w; p < 32 * w + 32; p++) {
      float v1 = Mb[p * O_ + lane];
      float v2 = Mb[p * O_ + 64 + lane];
      float2 mv; mv.x = v1; mv.y = v2;
      *(float2*)&Mlds[p * O_ + 2 * lane] = mv;
      P1 += (double)v1;
      P2 += (double)v2;
    }
    if (w == 0) { pq1 = P1; pq2 = P2; }
    else {
      partPd[w - 1][lane][0] = P1; partPd[w - 1][lane][1] = P2;
      __threadfence_block();
      if (lane == 0) atomicAdd(&stageDone, 1);
    }
  }

// one gumbel row r -> Glds (keys from Klds; wave-uniform broadcast reads)
#define GUMROW(r) {                                                    \
    uint32_t k0j = Klds[2 * (r)], k1j = Klds[2 * (r) + 1];             \
    uint32_t w0, w1;                                                   \
    uint32_t m1 = (uint32_t)(b * O_ + lane);                           \
    tf2x32(k0j, k1j, 0u, m1, &w0, &w1);                                \
    float g1 = gumbel_bits(w0 ^ w1);                                   \
    tf2x32(k0j, k1j, 0u, m1 + 64u, &w0, &w1);                          \
    float g2 = gumbel_bits(w0 ^ w1);                                   \
    float2 gv; gv.x = g1; gv.y = g2;                                   \
    *(float2*)&Glds[(r) * O_ + 2 * lane] = gv;                         \
  }

  // ---------- gumbel producers (waves 4-7 coop; solo on 5-7 only) ----------
  if (w >= 4) {
    const int ww = w - 4;
    // chunk 0: rows 2ww, 2ww+1 cooperatively; 4th finisher raises flagG[0]
    GUMROW(2 * ww) GUMROW(2 * ww + 1)
    __threadfence_block();
    if (lane == 0) {
      int old = atomicAdd(&g0cnt, 1);
      if (old == 3) vFlagG[0] = 1;
    }
    // chunk 1: rows 8+2ww, 9+2ww
    GUMROW(8 + 2 * ww) GUMROW(9 + 2 * ww)
    __threadfence_block();
    if (lane == 0) {
      int old = atomicAdd(&g1cnt, 1);
      if (old == 3) vFlagG[1] = 1;
    }
    // solo chunks 2..15 on waves 5-7 (wave 4 parks -> SIMD 0 free for chain)
    if (w >= 5) {
#pragma unroll 1
      for (int c = w - 3; c < 16; c += 3) {
        for (int r = 8 * c; r < 8 * c + 8; r++) GUMROW(r)
        __threadfence_block();
        if (lane == 0) vFlagG[c] = 1;
      }
    }
  }
#undef GUMROW

// full serial-chain iteration (fast path f32; exact fallback from f64 Pd)
#define CHAIN_ITER(jv, LOADG, SLOT) {                                     \
      uint32_t kk1 = (mono32(z1) & 0xFFFFFF80u) | idx1;                   \
      uint32_t kk2 = (mono32(z2) & 0xFFFFFF80u) | idx2;                   \
      uint32_t km = kk1 > kk2 ? kk1 : kk2;                                \
      km = wredmaxu_to63(km);                                             \
      uint32_t kmax = (uint32_t)__builtin_amdgcn_readlane((int)km, 63);   \
      int pos = 127 - (int)(kmax & 127u);                                 \
      float2 mv = *(float2*)&Mlds[pos * O_ + 2 * lane];                   \
      uint32_t mono_t = kmax & 0xFFFFFF80u;                               \
      uint32_t zb = (mono_t & 0x80000000u) ? (mono_t ^ 0x80000000u)       \
                                           : ~mono_t;                    \
      float thr = __uint_as_float(zb) - 1e-2f;                            \
      unsigned long long n1 = __ballot(z1 > thr);                         \
      unsigned long long n2 = __ballot(z2 > thr);                         \
      float2 gnext = gcur;                                                \
      if (LOADG) gnext = *(float2*)&Glds[((jv) + 1) * O_ + 2 * lane];     \
      if (__popcll(n1) + __popcll(n2) != 1) {                             \
        float pm1 = ((bmk1 >> lane) & 1) ? NEGF : ((float)Pd1 + b1f);     \
        float pm2 = ((bmk2 >> lane) & 1) ? NEGF : ((float)Pd2 + b2f);     \
        float mx = wredmaxf(fmaxf(pm1, pm2));                             \
        float s1e = pm1 - mx, s2e = pm2 - mx;                             \
        float ss = wredsumf(expf(s1e) + expf(s2e));                       \
        float lse = logf(ss);                                             \
        float y1 = (s1e - lse) + gcur.x;                                  \
        float y2 = (s2e - lse) + gcur.y;                                  \
        float ym = wredmaxf(fmaxf(y1, y2));                               \
        unsigned long long c1 = __ballot(y1 == ym);                       \
        unsigned long long c2 = __ballot(y2 == ym);                       \
        pos = c1 ? (__ffsll(c1) - 1) : (64 + __ffsll(c2) - 1);            \
        mv = *(float2*)&Mlds[pos * O_ + 2 * lane];                        \
      }                                                                   \
      pk |= ((unsigned long long)(unsigned)pos) << (8 * (SLOT));          \
      bool sel1 = (lane == pos), sel2 = (lane + 64 == pos);               \
      if (pos < 64) bmk1 |= 1ull << pos; else bmk2 |= 1ull << (pos - 64); \
      Pd1 -= (double)mv.x;                                                \
      Pd2 -= (double)mv.y;                                                \
      s1 = sel1 ? NEGF : (s1 - mv.x);                                     \
      s2 = sel2 ? NEGF : (s2 - mv.y);                                     \
      gcur = gnext;                                                       \
      z1 = s1 + gcur.x;                                                   \
      z2 = s2 + gcur.y;                                                   \
    }

// iteration without next-z production (second-to-last step)
#define CHAIN_ITER_NZ(jv, SLOT) {                                         \
      uint32_t kk1 = (mono32(z1) & 0xFFFFFF80u) | idx1;                   \
      uint32_t kk2 = (mono32(z2) & 0xFFFFFF80u) | idx2;                   \
      uint32_t km = kk1 > kk2 ? kk1 : kk2;                                \
      km = wredmaxu_to63(km);                                             \
      uint32_t kmax = (uint32_t)__builtin_amdgcn_readlane((int)km, 63);   \
      int pos = 127 - (int)(kmax & 127u);                                 \
      float2 mv = *(float2*)&Mlds[pos * O_ + 2 * lane];                   \
      uint32_t mono_t = kmax & 0xFFFFFF80u;                               \
      uint32_t zb = (mono_t & 0x80000000u) ? (mono_t ^ 0x80000000u)       \
                                           : ~mono_t;                    \
      float thr = __uint_as_float(zb) - 1e-2f;                            \
      unsigned long long n1 = __ballot(z1 > thr);                         \
      unsigned long long n2 = __ballot(z2 > thr);                         \
      if (__popcll(n1) + __popcll(n2) != 1) {                             \
        float pm1 = ((bmk1 >> lane) & 1) ? NEGF : ((float)Pd1 + b1f);     \
        float pm2 = ((bmk2 >> lane) & 1) ? NEGF : ((float)Pd2 + b2f);     \
        float mx = wredmaxf(fmaxf(pm1, pm2));                             \
        float s1e = pm1 - mx, s2e = pm2 - mx;                             \
        float ss = wredsumf(expf(s1e) + expf(s2e));                       \
        float lse = logf(ss);                                             \
        float y1 = (s1e - lse) + gcur.x;                                  \
        float y2 = (s2e - lse) + gcur.y;                                  \
        float ym = wredmaxf(fmaxf(y1, y2));                               \
        unsigned long long c1 = __ballot(y1 == ym);                       \
        unsigned long long c2 = __ballot(y2 == ym);                       \
        pos = c1 ? (__ffsll(c1) - 1) : (64 + __ffsll(c2) - 1);            \
        mv = *(float2*)&Mlds[pos * O_ + 2 * lane];                        \
      }                                                                   \
      pk |= ((unsigned long long)(unsigned)pos) << (8 * (SLOT));          \
      if (pos < 64) bmk1 |= 1ull << pos; else bmk2 |= 1ull << (pos - 64); \
      Pd1 -= (double)mv.x;                                                \
      Pd2 -= (double)mv.y;                                                \
    }

#define SNAPSHOT(sc) {                                                    \
      double2 pv; pv.x = Pd1; pv.y = Pd2;                                 \
      *(double2*)&snapPd[((sc) * 64 + lane) * 2] = pv;                    \
      if (lane == 0) { snapMk[(sc) * 2] = bmk1;                           \
                       snapMk[(sc) * 2 + 1] = bmk2; }                     \
    }

  // ---------- wave 0: Pd combine + serial chain ----------
  if (w == 0) {
    __builtin_amdgcn_s_setprio(3);
    while (*vSD < 3) __builtin_amdgcn_s_sleep(1);
    __threadfence_block();

    // fixed combine order q0+q1+q2+q3 (each quarter ascending p)
    double Pd1 = ((pq1 + partPd[0][lane][0]) + partPd[1][lane][0]) +
                 partPd[2][lane][0];
    double Pd2 = ((pq2 + partPd[0][lane][1]) + partPd[1][lane][1]) +
                 partPd[2][lane][1];

    unsigned long long bmk1 = 0ull, bmk2 = 0ull;
    while (vFlagG[0] == 0) __builtin_amdgcn_s_sleep(1);
    __threadfence_block();
    float2 gcur = *(float2*)&Glds[2 * lane];

    const uint32_t idx1 = 127u - (uint32_t)lane;   // half-1 key index
    const uint32_t idx2 = 63u - (uint32_t)lane;    // half-2 key index
    float s1 = (float)Pd1 + b1f;
    float s2 = (float)Pd2 + b2f;
    float z1 = s1 + gcur.x, z2 = s2 + gcur.y;      // unmasked at j=0
    int gval = 0;
    unsigned long long pk;

    // main chunks c = 0..14 (8 steps each); release of c-1 deferred to the
    // top of chunk c (shares the acquire fence)
#pragma unroll 1
    for (int c = 0; c < 15; ++c) {
      if (gval == 0) {            // gate flagG[c+1] (covers gnext at j=8c+7)
        while (vFlagG[c + 1] == 0) __builtin_amdgcn_s_sleep(1);
      }
      __threadfence_block();
      if (c > 0 && lane == 0) vRel[c - 1] = 1;
      SNAPSHOT(c)
      pk = 0ull;
#pragma unroll
      for (int jj = 0; jj < 8; ++jj) {
        CHAIN_ITER(8 * c + jj, 1, jj)
        if (jj == 6 && c <= 13) gval = vFlagG[c + 2];  // prefetch next gate
      }
      if (lane == 0) posPk[c] = pk;
    }
    __threadfence_block();
    if (lane == 0) vRel[14] = 1;

    // chunk 15: j=120..123
    SNAPSHOT(15)
    pk = 0ull;
    CHAIN_ITER(120, 1, 0) CHAIN_ITER(121, 1, 1)
    CHAIN_ITER(122, 1, 2) CHAIN_ITER(123, 1, 3)
    if (lane == 0) posPk[15] = pk;
    __threadfence_block();
    if (lane == 0) vRel[15] = 1;

    // 1-step chunks 16,17 (full), 18 (no-z), 19 (forced)
    SNAPSHOT(16)
    pk = 0ull; CHAIN_ITER(124, 1, 0)
    if (lane == 0) posPk[16] = pk;
    __threadfence_block();
    if (lane == 0) vRel[16] = 1;

    SNAPSHOT(17)
    pk = 0ull; CHAIN_ITER(125, 1, 0)
    if (lane == 0) posPk[17] = pk;
    __threadfence_block();
    if (lane == 0) vRel[17] = 1;

    SNAPSHOT(18)
    pk = 0ull; CHAIN_ITER_NZ(126, 0)
    if (lane == 0) posPk[18] = pk;
    __threadfence_block();
    if (lane == 0) vRel[18] = 1;

    SNAPSHOT(19)
    {
      unsigned long long r1 = ~bmk1, r2 = ~bmk2;   // exactly one bit set
      int pos = r1 ? (__ffsll(r1) - 1) : (64 + __ffsll(r2) - 1);
      if (lane == 0) posPk[19] = (unsigned long long)(unsigned)pos;
    }
    __threadfence_block();
    if (lane == 0) vRel[19] = 1;

    // out_pos from packed positions (posPk reads: same-wave DS order)
    {
      int j1 = 127 - lane, c1i, o1i;
      if (j1 < 120)      { c1i = j1 >> 3; o1i = j1 & 7; }
      else if (j1 < 124) { c1i = 15; o1i = j1 - 120; }
      else               { c1i = 16 + (j1 - 124); o1i = 0; }
      unsigned long long pka = posPk[c1i];
      out_pos[(size_t)b * O_ + lane] =
          (float)(int)((pka >> (8 * o1i)) & 127u);
      int j2 = 63 - lane;                      // always < 120
      unsigned long long pkb = posPk[j2 >> 3];
      out_pos[(size_t)b * O_ + 64 + lane] =
          (float)(int)((pkb >> (8 * (j2 & 7))) & 127u);
    }
  }
#undef CHAIN_ITER
#undef CHAIN_ITER_NZ
#undef SNAPSHOT

  // ---------- phase 3: rank/err/ls on 6 waves {1,2,3,5,6,7} ----------------
  // (wave 4 skips -> parks at the final barrier, leaving SIMD 0 to wave 0)
  if (w >= 1 && w != 4) {
    const int wi = (w < 4) ? (w - 1) : (w - 2);   // 0..5
    for (int c = wi; c < 20; c += 6) {
      while (vRel[c] == 0) __builtin_amdgcn_s_sleep(1);
      __threadfence_block();
      double2 pv = *(double2*)&snapPd[(c * 64 + lane) * 2];
      double P1 = pv.x, P2 = pv.y;
      unsigned long long bmk1 = snapMk[c * 2], bmk2 = snapMk[c * 2 + 1];
      unsigned long long pk = posPk[c];
      double ls_acc = 0.0;
      int err_acc = 0;
      int j0   = (c < 15) ? 8 * c : ((c == 15) ? 120 : (124 + (c - 16)));
      int jend = (c < 15) ? (j0 + 8) : ((c == 15) ? 124 : (j0 + 1));
      for (int j = j0; j < jend; j++) {
        float p1 = (float)P1 + b1f;   // bit-identical to consumer's score
        float p2 = (float)P2 + b2f;
        // u64 keys: (mono<<7)|(127-idx); larger = better rank, idx tie-break
        uint64_t K1 = ((uint64_t)mono32(p1) << 7) | (uint32_t)(127 - lane);
        uint64_t K2 = ((uint64_t)mono32(p2) << 7) | (uint32_t)(63 - lane);
        // bitwise (j+1)-th-largest: 39-iteration binary search (exact)
        uint64_t P = 0;
#pragma unroll
        for (int bit = 38; bit >= 0; --bit) {
          uint64_t cand = P | (1ull << bit);
          int c1 = __popcll(__ballot(K1 >= cand));
          int c2 = __popcll(__ballot(K2 >= cand));
          if (c1 + c2 > j) P = cand;   // at least j+1 keys >= cand
        }
        unsigned long long t1 = __ballot(K1 == P), t2 = __ballot(K2 == P);
        int topl, msk;
        if (t1) { topl = __ffsll(t1) - 1; msk = (int)((bmk1 >> topl) & 1); }
        else    { topl = __ffsll(t2) - 1; msk = (int)((bmk2 >> topl) & 1); }
        err_acc += msk;

        // ls: exact reference op order / identical DPP trees
        float pm1 = ((bmk1 >> lane) & 1) ? NEGF : p1;
        float pm2 = ((bmk2 >> lane) & 1) ? NEGF : p2;
        float mx = wredmaxf(fmaxf(pm1, pm2));
        float ss = wredsumf(expf(pm1 - mx) + expf(pm2 - mx));
        float lse = logf(ss);
        int pos = (int)((pk >> (8 * (j - j0))) & 127u);
        float psel = rl_f((pos < 64) ? p1 : p2, pos & 63);
        ls_acc += (double)((psel - mx) - lse);

        // advance state
        if (pos < 64) bmk1 |= 1ull << pos; else bmk2 |= 1ull << (pos - 64);
        float2 mv = *(float2*)&Mlds[pos * O_ + 2 * lane];
        P1 -= (double)mv.x;
        P2 -= (double)mv.y;
      }
      if (lane == 0) { lsSlot[c] = ls_acc; errSlot[c] = err_acc; }
    }
  }
  __syncthreads();

  if (t == 0) {
    double lt = 0.0; int et = 0;
    for (int i = 0; i < 20; i++) { lt += lsSlot[i]; et += errSlot[i]; }
    out_ls[b]  = (float)lt;
    out_err[b] = (float)et;
  }
}

extern "C" void kernel_launch(void* const* d_in, const int* in_sizes, int n_in,
                              void* d_out, int out_size, void* d_ws, size_t ws_size,
                              hipStream_t stream) {
  const float* enc  = (const float*)d_in[0];
  const float* W    = (const float*)d_in[1];
  const float* bias = (const float*)d_in[2];
  float* out     = (float*)d_out;
  float* out_pos = out;                  // [256][128] positions (as f32)
  float* out_ls  = out + B_ * O_;        // [256]
  float* out_err = out + B_ * O_ + B_;   // [256]

  float* M = (float*)d_ws;
  const size_t needM = (size_t)B_ * O_ * O_ * sizeof(float);  // 16.7 MB
  int use_M = (ws_size >= needM) ? 1 : 0;

  if (use_M) build_M<<<dim3(O_, 4), 256, 0, stream>>>(enc, W, M);
  sampler<<<dim3(B_), 512, 0, stream>>>(M, bias, enc, W, use_M,
                                        out_pos, out_ls, out_err);
}

// Round 11
// 137.012 us; speedup vs baseline: 1.0648x; 1.0648x over previous
//
#include <hip/hip_runtime.h>
#include <stdint.h>

#define B_   256
#define O_   128
#define D_   128
#define IN_  16384
#define NEGF (-9.0e15f)
#define TINYF 1.1754943508222875e-38f

// ---------------- threefry2x32 (JAX partitionable, 20 rounds) ----------------
__device__ __forceinline__ void tf2x32(uint32_t k0, uint32_t k1,
                                       uint32_t x0, uint32_t x1,
                                       uint32_t* o0, uint32_t* o1) {
  uint32_t k2 = k0 ^ k1 ^ 0x1BD11BDAu;
#define TFR(r) { x0 += x1; x1 = (x1 << (r)) | (x1 >> (32 - (r))); x1 ^= x0; }
  x0 += k0; x1 += k1;
  TFR(13) TFR(15) TFR(26) TFR(6)
  x0 += k1; x1 += k2 + 1u;
  TFR(17) TFR(29) TFR(16) TFR(24)
  x0 += k2; x1 += k0 + 2u;
  TFR(13) TFR(15) TFR(26) TFR(6)
  x0 += k0; x1 += k1 + 3u;
  TFR(17) TFR(29) TFR(16) TFR(24)
  x0 += k1; x1 += k2 + 4u;
  TFR(13) TFR(15) TFR(26) TFR(6)
  x0 += k2; x1 += k0 + 5u;
#undef TFR
  *o0 = x0; *o1 = x1;
}

__device__ __forceinline__ float gumbel_bits(uint32_t bits) {
  float f = __uint_as_float((bits >> 9) | 0x3f800000u) - 1.0f;  // [0,1)
  float u = fmaxf(TINYF, f + TINYF);
  return -logf(-logf(u));
}

__device__ __forceinline__ uint32_t mono32(float x) {
  int b = __float_as_int(x);
  return (uint32_t)b ^ ((uint32_t)(b >> 31) | 0x80000000u);
}

__device__ __forceinline__ float rl_f(float v, int l) {
  return __int_as_float(__builtin_amdgcn_readlane(__float_as_int(v), l));
}

// DPP helpers (identical trees to the rounds 5-10 passing trajectory)
#define DPPF(x, ctrl) __int_as_float(__builtin_amdgcn_mov_dpp( \
    __float_as_int(x), (ctrl), 0xf, 0xf, true))
#define DPPU(x, ctrl) ((uint32_t)__builtin_amdgcn_mov_dpp( \
    (int)(x), (ctrl), 0xf, 0xf, true))

__device__ __forceinline__ float wredmaxf(float x) {
  x = fmaxf(x, DPPF(x, 0xB1));
  x = fmaxf(x, DPPF(x, 0x4E));
  x = fmaxf(x, DPPF(x, 0x141));
  x = fmaxf(x, DPPF(x, 0x140));
  x = fmaxf(x, DPPF(x, 0x142));   // row_bcast15
  x = fmaxf(x, DPPF(x, 0x143));   // row_bcast31
  return rl_f(x, 63);
}
__device__ __forceinline__ float wredsumf(float x) {
  x = x + DPPF(x, 0xB1);
  x = x + DPPF(x, 0x4E);
  x = x + DPPF(x, 0x141);
  x = x + DPPF(x, 0x140);
  x = x + DPPF(x, 0x142);
  x = x + DPPF(x, 0x143);
  return rl_f(x, 63);
}
// u32 max over 64 lanes, same lane-movement tree (validated geometry)
__device__ __forceinline__ uint32_t wredmaxu_to63(uint32_t x) {
  uint32_t t;
  t = DPPU(x, 0xB1);  x = x > t ? x : t;
  t = DPPU(x, 0x4E);  x = x > t ? x : t;
  t = DPPU(x, 0x141); x = x > t ? x : t;
  t = DPPU(x, 0x140); x = x > t ? x : t;
  t = DPPU(x, 0x142); x = x > t ? x : t;
  t = DPPU(x, 0x143); x = x > t ? x : t;
  return x;
}

// ---------------- Kernel A: M[b][p][o] = <enc[b,p,:], W[o, p*D:(p+1)*D]> ----
// (validated: 64o x 128b tiles, W half-tile in LDS, enc streamed+prefetch)
__global__ __launch_bounds__(256, 2) void build_M(
    const float* __restrict__ enc, const float* __restrict__ W,
    float* __restrict__ M) {
  const int p   = blockIdx.x;
  const int og0 = (blockIdx.y & 1) * 64;    // o-half base
  const int b0  = (blockIdx.y >> 1) * 128;  // b-half base
  const int t   = threadIdx.x;

  __shared__ float Ws[64 * 132];            // 33.8 KB

  {
    const int rgrp = t >> 5;
    const int c16  = t & 31;
#pragma unroll
    for (int k = 0; k < 8; k++) {
      int row = k * 8 + rgrp;
      *(float4*)(Ws + row * 132 + c16 * 4) =
          *(const float4*)(W + (size_t)(og0 + row) * IN_ + p * D_ + c16 * 4);
    }
  }

  const int og = t & 15;
  const int bg = t >> 4;

  const float* eb = enc + ((size_t)(b0 + bg) * O_ + p) * D_;
  const size_t bstride = (size_t)16 * O_ * D_;

  float4 ev[8], evn[8];
#pragma unroll
  for (int bi = 0; bi < 8; bi++)
    ev[bi] = *(const float4*)(eb + bi * bstride);

  __syncthreads();

  float acc0[8][4] = {}, acc1[8][4] = {};

  for (int dc = 0; dc < 128; dc += 4) {
    if (dc < 124) {
#pragma unroll
      for (int bi = 0; bi < 8; bi++)
        evn[bi] = *(const float4*)(eb + bi * bstride + dc + 4);
    }
    float4 wv[4];
#pragma unroll
    for (int oi = 0; oi < 4; oi++)
      wv[oi] = *(const float4*)(Ws + (og + 16 * oi) * 132 + dc);
#pragma unroll
    for (int bi = 0; bi < 8; bi++)
#pragma unroll
      for (int oi = 0; oi < 4; oi++) {
        acc0[bi][oi] += ev[bi].x * wv[oi].x;
        acc1[bi][oi] += ev[bi].y * wv[oi].y;
        acc0[bi][oi] += ev[bi].z * wv[oi].z;
        acc1[bi][oi] += ev[bi].w * wv[oi].w;
      }
#pragma unroll
    for (int bi = 0; bi < 8; bi++) ev[bi] = evn[bi];
  }

#pragma unroll
  for (int bi = 0; bi < 8; bi++) {
    int b = b0 + bg + 16 * bi;
#pragma unroll
    for (int oi = 0; oi < 4; oi++) {
      int o = og0 + og + 16 * oi;
      M[((size_t)b * O_ + p) * O_ + o] = acc0[bi][oi] + acc1[bi][oi];
    }
  }
}

// ---------------- Kernel S: pipelined sampler v6 (best validated) -----------
// Structure (locked after v9-null / v10-regression bracketing):
//   waves 0-3 : stage Mlds quarter q=w + f64 partial column sums
//   waves 4-7 : gumbel (coop chunks 0,1; solo 2..15, c = 2+(w-4)+4k)
//   wave 0    : serial chain: packed-key u32 argmax (pos decoded from the
//               DPP-tree result), speculative Mlds row read, f32 running
//               score fast path, exact-reference fallback from f64 Pd;
//               2-level unrolled loop; packed posPk; deferred releases;
//               forced last step.
//   waves 1-7 : phase-3 rank/err/ls over 20 chunks (chunk = w-1+7k).
// All selection/ls/err numerics bit-identical to the validated trajectory.
__global__ __launch_bounds__(512, 1) void sampler(
    const float* __restrict__ M, const float* __restrict__ bias,
    const float* __restrict__ enc, const float* __restrict__ W, int use_M,
    float* __restrict__ out_pos, float* __restrict__ out_ls,
    float* __restrict__ out_err) {
  const int b = blockIdx.x;
  const int t = threadIdx.x;
  const int lane = t & 63;
  const int w = t >> 6;

  // interleaved: Mlds[p*128 + 2*k + h] = M[b][p][h*64+k]
  __shared__ float  Mlds[O_ * O_];          // 64 KB
  __shared__ float  Glds[O_ * O_];          // 64 KB, Glds[j*128+2*lane+h]
  __shared__ double snapPd[20 * 64 * 2];    // 20 KB
  __shared__ unsigned long long snapMk[20 * 2];
  __shared__ unsigned long long posPk[20];  // packed positions per chunk
  __shared__ double lsSlot[20];
  __shared__ int    errSlot[20];
  __shared__ int    flagG[16];              // gumbel chunk ready
  __shared__ int    chainRel[20];           // chain chunk released
  __shared__ int    stageDone;              // staging waves 1-3 done count
  __shared__ int    g0cnt, g1cnt;           // coop chunk-0/1 counters
  __shared__ double partPd[3][64][2];       // quarters 1-3 f64 column sums
  __shared__ uint32_t Klds[O_ * 2];         // step keys

  volatile int* vFlagG = flagG;
  volatile int* vRel   = chainRel;
  volatile int* vSD    = &stageDone;

  const float b1f = bias[lane], b2f = bias[lane + 64];

  // ---------- init: flags + step-key table, then start barrier -------------
  if (t < O_) {
    uint32_t a, bb;
    tf2x32(0u, 42u, 0u, (uint32_t)t, &a, &bb);
    Klds[2 * t] = a; Klds[2 * t + 1] = bb;
  }
  if (t < 16) flagG[t] = 0;
  if (t >= 32 && t < 52) chainRel[t - 32] = 0;
  if (t == 64) stageDone = 0;
  if (t == 65) g0cnt = 0;
  if (t == 66) g1cnt = 0;
  __syncthreads();

  // ---------- staging (+ f64 partial column sums), waves 0-3 ----------
  double pq1 = 0.0, pq2 = 0.0;   // wave-0 in-register quarter partial
  if (!use_M) {
    for (int idx = t; idx < O_ * O_; idx += 512) {
      int p = idx >> 7, o = idx & 127;
      const float* er = enc + ((size_t)b * O_ + p) * D_;
      const float* wr = W + (size_t)o * IN_ + p * D_;
      float s = 0.f;
      for (int d = 0; d < D_; d += 4) {
        float4 e4 = *(const float4*)(er + d);
        float4 w4 = *(const float4*)(wr + d);
        s += e4.x * w4.x + e4.y * w4.y + e4.z * w4.z + e4.w * w4.w;
      }
      Mlds[p * O_ + ((o & 63) << 1) + (o >> 6)] = s;
    }
    __syncthreads();
    if (w < 4) {
      double P1 = 0.0, P2 = 0.0;
      for (int p = 32 * w; p < 32 * w + 32; p++) {
        float2 mv = *(float2*)&Mlds[p * O_ + 2 * lane];
        P1 += (double)mv.x;
        P2 += (double)mv.y;
      }
      if (w == 0) { pq1 = P1; pq2 = P2; }
      else {
        partPd[w - 1][lane][0] = P1; partPd[w - 1][lane][1] = P2;
        __threadfence_block();
        if (lane == 0) atomicAdd(&stageDone, 1);
      }
    }
  } else if (w < 4) {
    const float* Mb = M + (size_t)b * O_ * O_;
    double P1 = 0.0, P2 = 0.0;
    for (int p = 32 * w; p < 32 * w + 32; p++) {
      float v1 = Mb[p * O_ + lane];
      float v2 = Mb[p * O_ + 64 + lane];
      float2 mv; mv.x = v1; mv.y = v2;
      *(float2*)&Mlds[p * O_ + 2 * lane] = mv;
      P1 += (double)v1;
      P2 += (double)v2;
    }
    if (w == 0) { pq1 = P1; pq2 = P2; }
    else {
      partPd[w - 1][lane][0] = P1; partPd[w - 1][lane][1] = P2;
      __threadfence_block();
      if (lane == 0) atomicAdd(&stageDone, 1);
    }
  }

// one gumbel row r -> Glds (keys from Klds; wave-uniform broadcast reads)
#define GUMROW(r) {                                                    \
    uint32_t k0j = Klds[2 * (r)], k1j = Klds[2 * (r) + 1];             \
    uint32_t w0, w1;                                                   \
    uint32_t m1 = (uint32_t)(b * O_ + lane);                           \
    tf2x32(k0j, k1j, 0u, m1, &w0, &w1);                                \
    float g1 = gumbel_bits(w0 ^ w1);                                   \
    tf2x32(k0j, k1j, 0u, m1 + 64u, &w0, &w1);                          \
    float g2 = gumbel_bits(w0 ^ w1);                                   \
    float2 gv; gv.x = g1; gv.y = g2;                                   \
    *(float2*)&Glds[(r) * O_ + 2 * lane] = gv;                         \
  }

  // ---------- gumbel producers (waves 4-7) ----------
  if (w >= 4) {
    const int ww = w - 4;
    // chunk 0: rows 2ww, 2ww+1 cooperatively; 4th finisher raises flagG[0]
    GUMROW(2 * ww) GUMROW(2 * ww + 1)
    __threadfence_block();
    if (lane == 0) {
      int old = atomicAdd(&g0cnt, 1);
      if (old == 3) vFlagG[0] = 1;
    }
    // chunk 1: rows 8+2ww, 9+2ww
    GUMROW(8 + 2 * ww) GUMROW(9 + 2 * ww)
    __threadfence_block();
    if (lane == 0) {
      int old = atomicAdd(&g1cnt, 1);
      if (old == 3) vFlagG[1] = 1;
    }
    // solo chunks 2..15
#pragma unroll 1
    for (int c = 2 + ww; c < 16; c += 4) {
      for (int r = 8 * c; r < 8 * c + 8; r++) GUMROW(r)
      __threadfence_block();
      if (lane == 0) vFlagG[c] = 1;
    }
  }
#undef GUMROW

// full serial-chain iteration (fast path f32; exact fallback from f64 Pd)
#define CHAIN_ITER(jv, LOADG, SLOT) {                                     \
      uint32_t kk1 = (mono32(z1) & 0xFFFFFF80u) | idx1;                   \
      uint32_t kk2 = (mono32(z2) & 0xFFFFFF80u) | idx2;                   \
      uint32_t km = kk1 > kk2 ? kk1 : kk2;                                \
      km = wredmaxu_to63(km);                                             \
      uint32_t kmax = (uint32_t)__builtin_amdgcn_readlane((int)km, 63);   \
      int pos = 127 - (int)(kmax & 127u);                                 \
      float2 mv = *(float2*)&Mlds[pos * O_ + 2 * lane];                   \
      uint32_t mono_t = kmax & 0xFFFFFF80u;                               \
      uint32_t zb = (mono_t & 0x80000000u) ? (mono_t ^ 0x80000000u)       \
                                           : ~mono_t;                    \
      float thr = __uint_as_float(zb) - 1e-2f;                            \
      unsigned long long n1 = __ballot(z1 > thr);                         \
      unsigned long long n2 = __ballot(z2 > thr);                         \
      float2 gnext = gcur;                                                \
      if (LOADG) gnext = *(float2*)&Glds[((jv) + 1) * O_ + 2 * lane];     \
      if (__popcll(n1) + __popcll(n2) != 1) {                             \
        float pm1 = ((bmk1 >> lane) & 1) ? NEGF : ((float)Pd1 + b1f);     \
        float pm2 = ((bmk2 >> lane) & 1) ? NEGF : ((float)Pd2 + b2f);     \
        float mx = wredmaxf(fmaxf(pm1, pm2));                             \
        float s1e = pm1 - mx, s2e = pm2 - mx;                             \
        float ss = wredsumf(expf(s1e) + expf(s2e));                       \
        float lse = logf(ss);                                             \
        float y1 = (s1e - lse) + gcur.x;                                  \
        float y2 = (s2e - lse) + gcur.y;                                  \
        float ym = wredmaxf(fmaxf(y1, y2));                               \
        unsigned long long c1 = __ballot(y1 == ym);                       \
        unsigned long long c2 = __ballot(y2 == ym);                       \
        pos = c1 ? (__ffsll(c1) - 1) : (64 + __ffsll(c2) - 1);            \
        mv = *(float2*)&Mlds[pos * O_ + 2 * lane];                        \
      }                                                                   \
      pk |= ((unsigned long long)(unsigned)pos) << (8 * (SLOT));          \
      bool sel1 = (lane == pos), sel2 = (lane + 64 == pos);               \
      if (pos < 64) bmk1 |= 1ull << pos; else bmk2 |= 1ull << (pos - 64); \
      Pd1 -= (double)mv.x;                                                \
      Pd2 -= (double)mv.y;                                                \
      s1 = sel1 ? NEGF : (s1 - mv.x);                                     \
      s2 = sel2 ? NEGF : (s2 - mv.y);                                     \
      gcur = gnext;                                                       \
      z1 = s1 + gcur.x;                                                   \
      z2 = s2 + gcur.y;                                                   \
    }

// iteration without next-z production (second-to-last step)
#define CHAIN_ITER_NZ(jv, SLOT) {                                         \
      uint32_t kk1 = (mono32(z1) & 0xFFFFFF80u) | idx1;                   \
      uint32_t kk2 = (mono32(z2) & 0xFFFFFF80u) | idx2;                   \
      uint32_t km = kk1 > kk2 ? kk1 : kk2;                                \
      km = wredmaxu_to63(km);                                             \
      uint32_t kmax = (uint32_t)__builtin_amdgcn_readlane((int)km, 63);   \
      int pos = 127 - (int)(kmax & 127u);                                 \
      float2 mv = *(float2*)&Mlds[pos * O_ + 2 * lane];                   \
      uint32_t mono_t = kmax & 0xFFFFFF80u;                               \
      uint32_t zb = (mono_t & 0x80000000u) ? (mono_t ^ 0x80000000u)       \
                                           : ~mono_t;                    \
      float thr = __uint_as_float(zb) - 1e-2f;                            \
      unsigned long long n1 = __ballot(z1 > thr);                         \
      unsigned long long n2 = __ballot(z2 > thr);                         \
      if (__popcll(n1) + __popcll(n2) != 1) {                             \
        float pm1 = ((bmk1 >> lane) & 1) ? NEGF : ((float)Pd1 + b1f);     \
        float pm2 = ((bmk2 >> lane) & 1) ? NEGF : ((float)Pd2 + b2f);     \
        float mx = wredmaxf(fmaxf(pm1, pm2));                             \
        float s1e = pm1 - mx, s2e = pm2 - mx;                             \
        float ss = wredsumf(expf(s1e) + expf(s2e));                       \
        float lse = logf(ss);                                             \
        float y1 = (s1e - lse) + gcur.x;                                  \
        float y2 = (s2e - lse) + gcur.y;                                  \
        float ym = wredmaxf(fmaxf(y1, y2));                               \
        unsigned long long c1 = __ballot(y1 == ym);                       \
        unsigned long long c2 = __ballot(y2 == ym);                       \
        pos = c1 ? (__ffsll(c1) - 1) : (64 + __ffsll(c2) - 1);            \
        mv = *(float2*)&Mlds[pos * O_ + 2 * lane];                        \
      }                                                                   \
      pk |= ((unsigned long long)(unsigned)pos) << (8 * (SLOT));          \
      if (pos < 64) bmk1 |= 1ull << pos; else bmk2 |= 1ull << (pos - 64); \
      Pd1 -= (double)mv.x;                                                \
      Pd2 -= (double)mv.y;                                                \
    }

#define SNAPSHOT(sc) {                                                    \
      double2 pv; pv.x = Pd1; pv.y = Pd2;                                 \
      *(double2*)&snapPd[((sc) * 64 + lane) * 2] = pv;                    \
      if (lane == 0) { snapMk[(sc) * 2] = bmk1;                           \
                       snapMk[(sc) * 2 + 1] = bmk2; }                     \
    }

  // ---------- wave 0: Pd combine + serial chain ----------
  if (w == 0) {
    __builtin_amdgcn_s_setprio(3);
    while (*vSD < 3) __builtin_amdgcn_s_sleep(1);
    __threadfence_block();

    // fixed combine order q0+q1+q2+q3 (each quarter ascending p)
    double Pd1 = ((pq1 + partPd[0][lane][0]) + partPd[1][lane][0]) +
                 partPd[2][lane][0];
    double Pd2 = ((pq2 + partPd[0][lane][1]) + partPd[1][lane][1]) +
                 partPd[2][lane][1];

    unsigned long long bmk1 = 0ull, bmk2 = 0ull;
    while (vFlagG[0] == 0) __builtin_amdgcn_s_sleep(1);
    __threadfence_block();
    float2 gcur = *(float2*)&Glds[2 * lane];

    const uint32_t idx1 = 127u - (uint32_t)lane;   // half-1 key index
    const uint32_t idx2 = 63u - (uint32_t)lane;    // half-2 key index
    float s1 = (float)Pd1 + b1f;
    float s2 = (float)Pd2 + b2f;
    float z1 = s1 + gcur.x, z2 = s2 + gcur.y;      // unmasked at j=0
    int gval = 0;
    unsigned long long pk;

    // main chunks c = 0..14 (8 steps each); release of c-1 deferred to the
    // top of chunk c (shares the acquire fence)
#pragma unroll 1
    for (int c = 0; c < 15; ++c) {
      if (gval == 0) {            // gate flagG[c+1] (covers gnext at j=8c+7)
        while (vFlagG[c + 1] == 0) __builtin_amdgcn_s_sleep(1);
      }
      __threadfence_block();
      if (c > 0 && lane == 0) vRel[c - 1] = 1;
      SNAPSHOT(c)
      pk = 0ull;
#pragma unroll
      for (int jj = 0; jj < 8; ++jj) {
        CHAIN_ITER(8 * c + jj, 1, jj)
        if (jj == 6 && c <= 13) gval = vFlagG[c + 2];  // prefetch next gate
      }
      if (lane == 0) posPk[c] = pk;
    }
    __threadfence_block();
    if (lane == 0) vRel[14] = 1;

    // chunk 15: j=120..123
    SNAPSHOT(15)
    pk = 0ull;
    CHAIN_ITER(120, 1, 0) CHAIN_ITER(121, 1, 1)
    CHAIN_ITER(122, 1, 2) CHAIN_ITER(123, 1, 3)
    if (lane == 0) posPk[15] = pk;
    __threadfence_block();
    if (lane == 0) vRel[15] = 1;

    // 1-step chunks 16,17 (full), 18 (no-z), 19 (forced)
    SNAPSHOT(16)
    pk = 0ull; CHAIN_ITER(124, 1, 0)
    if (lane == 0) posPk[16] = pk;
    __threadfence_block();
    if (lane == 0) vRel[16] = 1;

    SNAPSHOT(17)
    pk = 0ull; CHAIN_ITER(125, 1, 0)
    if (lane == 0) posPk[17] = pk;
    __threadfence_block();
    if (lane == 0) vRel[17] = 1;

    SNAPSHOT(18)
    pk = 0ull; CHAIN_ITER_NZ(126, 0)
    if (lane == 0) posPk[18] = pk;
    __threadfence_block();
    if (lane == 0) vRel[18] = 1;

    SNAPSHOT(19)
    {
      unsigned long long r1 = ~bmk1, r2 = ~bmk2;   // exactly one bit set
      int pos = r1 ? (__ffsll(r1) - 1) : (64 + __ffsll(r2) - 1);
      if (lane == 0) posPk[19] = (unsigned long long)(unsigned)pos;
    }
    __threadfence_block();
    if (lane == 0) vRel[19] = 1;

    // out_pos from packed positions (posPk reads: same-wave DS order)
    {
      int j1 = 127 - lane, c1i, o1i;
      if (j1 < 120)      { c1i = j1 >> 3; o1i = j1 & 7; }
      else if (j1 < 124) { c1i = 15; o1i = j1 - 120; }
      else               { c1i = 16 + (j1 - 124); o1i = 0; }
      unsigned long long pka = posPk[c1i];
      out_pos[(size_t)b * O_ + lane] =
          (float)(int)((pka >> (8 * o1i)) & 127u);
      int j2 = 63 - lane;                      // always < 120
      unsigned long long pkb = posPk[j2 >> 3];
      out_pos[(size_t)b * O_ + 64 + lane] =
          (float)(int)((pkb >> (8 * (j2 & 7))) & 127u);
    }
  }
#undef CHAIN_ITER
#undef CHAIN_ITER_NZ
#undef SNAPSHOT

  // ---------- phase 3: rank/err/ls chunks, concurrent with the chain -------
  if (w >= 1) {
    for (int c = w - 1; c < 20; c += 7) {
      while (vRel[c] == 0) __builtin_amdgcn_s_sleep(1);
      __threadfence_block();
      double2 pv = *(double2*)&snapPd[(c * 64 + lane) * 2];
      double P1 = pv.x, P2 = pv.y;
      unsigned long long bmk1 = snapMk[c * 2], bmk2 = snapMk[c * 2 + 1];
      unsigned long long pk = posPk[c];
      double ls_acc = 0.0;
      int err_acc = 0;
      int j0   = (c < 15) ? 8 * c : ((c == 15) ? 120 : (124 + (c - 16)));
      int jend = (c < 15) ? (j0 + 8) : ((c == 15) ? 124 : (j0 + 1));
      for (int j = j0; j < jend; j++) {
        float p1 = (float)P1 + b1f;   // bit-identical to consumer's score
        float p2 = (float)P2 + b2f;
        // u64 keys: (mono<<7)|(127-idx); larger = better rank, idx tie-break
        uint64_t K1 = ((uint64_t)mono32(p1) << 7) | (uint32_t)(127 - lane);
        uint64_t K2 = ((uint64_t)mono32(p2) << 7) | (uint32_t)(63 - lane);
        // bitwise (j+1)-th-largest: 39-iteration binary search (exact)
        uint64_t P = 0;
#pragma unroll
        for (int bit = 38; bit >= 0; --bit) {
          uint64_t cand = P | (1ull << bit);
          int c1 = __popcll(__ballot(K1 >= cand));
          int c2 = __popcll(__ballot(K2 >= cand));
          if (c1 + c2 > j) P = cand;   // at least j+1 keys >= cand
        }
        unsigned long long t1 = __ballot(K1 == P), t2 = __ballot(K2 == P);
        int topl, msk;
        if (t1) { topl = __ffsll(t1) - 1; msk = (int)((bmk1 >> topl) & 1); }
        else    { topl = __ffsll(t2) - 1; msk = (int)((bmk2 >> topl) & 1); }
        err_acc += msk;

        // ls: exact reference op order / identical DPP trees
        float pm1 = ((bmk1 >> lane) & 1) ? NEGF : p1;
        float pm2 = ((bmk2 >> lane) & 1) ? NEGF : p2;
        float mx = wredmaxf(fmaxf(pm1, pm2));
        float ss = wredsumf(expf(pm1 - mx) + expf(pm2 - mx));
        float lse = logf(ss);
        int pos = (int)((pk >> (8 * (j - j0))) & 127u);
        float psel = rl_f((pos < 64) ? p1 : p2, pos & 63);
        ls_acc += (double)((psel - mx) - lse);

        // advance state
        if (pos < 64) bmk1 |= 1ull << pos; else bmk2 |= 1ull << (pos - 64);
        float2 mv = *(float2*)&Mlds[pos * O_ + 2 * lane];
        P1 -= (double)mv.x;
        P2 -= (double)mv.y;
      }
      if (lane == 0) { lsSlot[c] = ls_acc; errSlot[c] = err_acc; }
    }
  }
  __syncthreads();

  if (t == 0) {
    double lt = 0.0; int et = 0;
    for (int i = 0; i < 20; i++) { lt += lsSlot[i]; et += errSlot[i]; }
    out_ls[b]  = (float)lt;
    out_err[b] = (float)et;
  }
}

extern "C" void kernel_launch(void* const* d_in, const int* in_sizes, int n_in,
                              void* d_out, int out_size, void* d_ws, size_t ws_size,
                              hipStream_t stream) {
  const float* enc  = (const float*)d_in[0];
  const float* W    = (const float*)d_in[1];
  const float* bias = (const float*)d_in[2];
  float* out     = (float*)d_out;
  float* out_pos = out;                  // [256][128] positions (as f32)
  float* out_ls  = out + B_ * O_;        // [256]
  float* out_err = out + B_ * O_ + B_;   // [256]

  float* M = (float*)d_ws;
  const size_t needM = (size_t)B_ * O_ * O_ * sizeof(float);  // 16.7 MB
  int use_M = (ws_size >= needM) ? 1 : 0;

  if (use_M) build_M<<<dim3(O_, 4), 256, 0, stream>>>(enc, W, M);
  sampler<<<dim3(B_), 512, 0, stream>>>(M, bias, enc, W, use_M,
                                        out_pos, out_ls, out_err);
}